// Round 4
// baseline (285.696 us; speedup 1.0000x reference)
//
#include <hip/hip_runtime.h>
#include <math.h>

#define DIMS 128
#define GD 256
#define MAXB 1024
#define NSLOT 8   // edge slots per reduce block (256 thr / 32 dim-groups)
#define PARTS 4   // blocks per graph in reduce phase
#define NBLK 256  // block decomposition for histogram/scatter
#define SCH 8192  // max edges per scatter chunk (>= ceil(E/NBLK))

typedef float vfloat4 __attribute__((ext_vector_type(4)));

// ---------- helpers ----------
__device__ __forceinline__ float4 ldnt(const float* p) {
    vfloat4 v = __builtin_nontemporal_load(reinterpret_cast<const vfloat4*>(p));
    return make_float4(v.x, v.y, v.z, v.w);
}
__device__ __forceinline__ float4 f4_add(float4 a, float4 b) {
    return make_float4(a.x + b.x, a.y + b.y, a.z + b.z, a.w + b.w);
}
__device__ __forceinline__ float4 f4_min(float4 a, float4 b) {
    return make_float4(fminf(a.x, b.x), fminf(a.y, b.y), fminf(a.z, b.z), fminf(a.w, b.w));
}
__device__ __forceinline__ float4 f4_max(float4 a, float4 b) {
    return make_float4(fmaxf(a.x, b.x), fmaxf(a.y, b.y), fmaxf(a.z, b.z), fmaxf(a.w, b.w));
}

template <int OP>
__device__ __forceinline__ float4 comb(float4 a, float4 b) {
    if (OP == 0) return f4_add(a, b);
    if (OP == 1) return f4_min(a, b);
    return f4_max(a, b);
}

// reduce the 8 edge-slots (stride 32 in tid) down to slot 0; result valid for tid<32
template <int OP>
__device__ __forceinline__ float4 slot_reduce(float4 v, float4* red) {
    int t = threadIdx.x;
    __syncthreads();
    red[t] = v;
    __syncthreads();
    for (int off = 128; off >= 32; off >>= 1) {
        if (t < off) red[t] = comb<OP>(red[t], red[t + off]);
        __syncthreads();
    }
    return red[t & 31];
}

#define ACC(v) do { \
    sm = f4_add(sm, v); \
    sq = f4_add(sq, make_float4((v).x*(v).x, (v).y*(v).y, (v).z*(v).z, (v).w*(v).w)); \
    mn = f4_min(mn, v); mx = f4_max(mx, v); } while (0)

// ---------- K1: per-block histogram + graph-id cache ----------
__global__ void __launch_bounds__(256)
hist2_kernel(const int* __restrict__ e_index, const int* __restrict__ batch,
             int E, int* __restrict__ hist2, unsigned short* __restrict__ eb) {
    __shared__ int lh[MAXB];
    for (int i = threadIdx.x; i < MAXB; i += 256) lh[i] = 0;
    __syncthreads();
    int b = blockIdx.x;
    int CH = (E + NBLK - 1) / NBLK;
    int lo = b * CH;
    int hi = min(E, lo + CH);
    for (int j = lo + threadIdx.x; j < hi; j += 256) {
        int node = e_index[E + j];       // e_index[1][j]
        int g = batch[node];
        eb[j] = (unsigned short)g;
        atomicAdd(&lh[g], 1);            // LDS atomic only
    }
    __syncthreads();
    for (int i = threadIdx.x; i < MAXB; i += 256)
        hist2[(size_t)b * MAXB + i] = lh[i];   // coalesced 4 KB per block
}

// ---------- K2: column-scan hist2 in place + count + offs (one block) ----------
__global__ void __launch_bounds__(1024)
scanall_kernel(int* __restrict__ hist2, int* __restrict__ count, int* __restrict__ offs) {
    int g = threadIdx.x;
    int s = 0;
    // 8-deep pipelined serial prefix down the column (break the load->use chain)
#pragma unroll 1
    for (int b0 = 0; b0 < NBLK; b0 += 8) {
        int v[8];
#pragma unroll
        for (int i = 0; i < 8; ++i) v[i] = hist2[(size_t)(b0 + i) * MAXB + g];
#pragma unroll
        for (int i = 0; i < 8; ++i) { hist2[(size_t)(b0 + i) * MAXB + g] = s; s += v[i]; }
    }
    count[g] = s;
    __shared__ int tmp[MAXB];
    tmp[g] = s;
    __syncthreads();
    for (int d = 1; d < MAXB; d <<= 1) {
        int x = (g >= d) ? tmp[g - d] : 0;
        __syncthreads();
        tmp[g] += x;
        __syncthreads();
    }
    offs[g] = tmp[g] - s;
}

// ---------- K3: LDS-binned scatter (no global atomics, coalesced run writes) ----------
__global__ void __launch_bounds__(256)
scatter_kernel(const unsigned short* __restrict__ eb, const int* __restrict__ hist2,
               const int* __restrict__ offs, int E, int* __restrict__ perm) {
    __shared__ int lhist[MAXB];
    __shared__ int lofs[MAXB];
    __shared__ int lcur[MAXB];
    __shared__ int lbase[MAXB];
    __shared__ int ws[256];
    __shared__ int bin[SCH];
    int b = blockIdx.x;
    int t = threadIdx.x;
    int CH = (E + NBLK - 1) / NBLK;
    int lo = b * CH;
    int hi = min(E, lo + CH);

    for (int i = t; i < MAXB; i += 256) {
        lhist[i] = 0;
        lbase[i] = offs[i] + hist2[(size_t)b * MAXB + i];
    }
    __syncthreads();
    // local count
    for (int j = lo + t; j < hi; j += 256) atomicAdd(&lhist[eb[j]], 1);
    __syncthreads();
    // local exclusive scan over 1024 bins (4 per thread + block scan)
    int base = t * 4;
    int c0 = lhist[base + 0], c1 = lhist[base + 1], c2 = lhist[base + 2], c3 = lhist[base + 3];
    int s0 = c0 + c1 + c2 + c3;
    ws[t] = s0;
    __syncthreads();
    for (int d = 1; d < 256; d <<= 1) {
        int x = (t >= d) ? ws[t - d] : 0;
        __syncthreads();
        ws[t] += x;
        __syncthreads();
    }
    int excl = ws[t] - s0;
    lofs[base + 0] = excl;
    lofs[base + 1] = excl + c0;
    lofs[base + 2] = excl + c0 + c1;
    lofs[base + 3] = excl + c0 + c1 + c2;
    lcur[base + 0] = excl;
    lcur[base + 1] = excl + c0;
    lcur[base + 2] = excl + c0 + c1;
    lcur[base + 3] = excl + c0 + c1 + c2;
    __syncthreads();
    // bin edge ids into LDS
    for (int j = lo + t; j < hi; j += 256) {
        int g = eb[j];
        int r = atomicAdd(&lcur[g], 1);
        bin[r] = j;
    }
    __syncthreads();
    // flush: 8-lane groups write each graph's run contiguously
    int grp = t >> 3, sub = t & 7;   // 32 groups of 8
    for (int g = grp; g < MAXB; g += 32) {
        int sfrom = lofs[g];
        int n = lcur[g] - sfrom;
        int dst = lbase[g];
        for (int k = sub; k < n; k += 8)
            perm[dst + k] = bin[sfrom + k];
    }
}

// ---------- K4: one block per (graph, part): partials {sum,min,max,sumsq} ----------
__global__ void __launch_bounds__(256)
reduce_kernel(const float* __restrict__ e, const int* __restrict__ perm,
              const int* __restrict__ offs, const int* __restrict__ count,
              float* __restrict__ pbuf) {
    int bid = blockIdx.x;
    int g = bid >> 2;                // PARTS == 4
    int p = bid & 3;
    int start = offs[g];
    int cnt = count[g];
    int chunk = (cnt + PARTS - 1) / PARTS;
    int base = start + p * chunk;
    int cnt_p = cnt - p * chunk;
    if (cnt_p > chunk) cnt_p = chunk;
    if (cnt_p < 0) cnt_p = 0;
    const int* pp = perm + base;

    int c = threadIdx.x & 31;   // dim group: dims 4c..4c+3
    int s = threadIdx.x >> 5;   // edge slot 0..7

    float4 sm = make_float4(0.f, 0.f, 0.f, 0.f);
    float4 sq = make_float4(0.f, 0.f, 0.f, 0.f);
    float4 mn = make_float4(INFINITY, INFINITY, INFINITY, INFINITY);
    float4 mx = make_float4(-INFINITY, -INFINITY, -INFINITY, -INFINITY);

    int i = s;
    // 4-row software pipeline: indices prefetched one quad ahead, 4 loads in flight
    if (i + 3 * NSLOT < cnt_p) {
        int ia0 = pp[i], ia1 = pp[i + NSLOT], ia2 = pp[i + 2 * NSLOT], ia3 = pp[i + 3 * NSLOT];
        while (true) {
            int ni = i + 4 * NSLOT;
            int na0 = 0, na1 = 0, na2 = 0, na3 = 0;
            bool nok = (ni + 3 * NSLOT < cnt_p);
            if (nok) { na0 = pp[ni]; na1 = pp[ni + NSLOT]; na2 = pp[ni + 2 * NSLOT]; na3 = pp[ni + 3 * NSLOT]; }
            float4 v0 = ldnt(e + (size_t)ia0 * DIMS + c * 4);
            float4 v1 = ldnt(e + (size_t)ia1 * DIMS + c * 4);
            float4 v2 = ldnt(e + (size_t)ia2 * DIMS + c * 4);
            float4 v3 = ldnt(e + (size_t)ia3 * DIMS + c * 4);
            ACC(v0); ACC(v1); ACC(v2); ACC(v3);
            i = ni;
            if (!nok) break;
            ia0 = na0; ia1 = na1; ia2 = na2; ia3 = na3;
        }
    }
    for (; i < cnt_p; i += NSLOT) {
        int r = pp[i];
        float4 v = ldnt(e + (size_t)r * DIMS + c * 4);
        ACC(v);
    }

    __shared__ float4 red[256];
    float4 smr = slot_reduce<0>(sm, red);
    float4 mnr = slot_reduce<1>(mn, red);
    float4 mxr = slot_reduce<2>(mx, red);
    float4 sqr = slot_reduce<0>(sq, red);

    if (threadIdx.x < 32) {
        float* row = pbuf + (size_t)bid * (4 * DIMS);
        int d0 = c * 4;
        *reinterpret_cast<float4*>(row + 0 * DIMS + d0) = smr;
        *reinterpret_cast<float4*>(row + 1 * DIMS + d0) = mnr;
        *reinterpret_cast<float4*>(row + 2 * DIMS + d0) = mxr;
        *reinterpret_cast<float4*>(row + 3 * DIMS + d0) = sqr;
    }
}

// ---------- K5: fused combine + GEMM; 8 graph rows per block ----------
__global__ void __launch_bounds__(256)
gemm_kernel(const float* __restrict__ pbuf, const int* __restrict__ count,
            const float* __restrict__ w, const float* __restrict__ bias,
            float* __restrict__ out, int B) {
    __shared__ float gl[8 * 512];
    int r0 = blockIdx.x * 8;
    int t = threadIdx.x;
    // combine PARTS partials and finalize straight into LDS
#pragma unroll
    for (int q = 0; q < 4; ++q) {
        int pair = q * 256 + t;      // 0..1023 = (r,d)
        int r = pair >> 7;           // 0..7
        int d = pair & 127;
        int g = r0 + r;
        float sm = 0.f, sq = 0.f, mnv = INFINITY, mxv = -INFINITY;
        int cnt = 0;
        if (g < B) {
            cnt = count[g];
            const float* pb = pbuf + (size_t)g * PARTS * 512;
#pragma unroll
            for (int p = 0; p < PARTS; ++p) {
                const float* row = pb + p * 512;
                sm += row[d];
                mnv = fminf(mnv, row[128 + d]);
                mxv = fmaxf(mxv, row[256 + d]);
                sq += row[384 + d];
            }
        }
        float fc = (float)cnt;
        float fcm = fmaxf(fc, 1.0f);
        float mean = sm / fcm;
        float vs = fmaxf(sq - sm * mean, 0.f);
        float sd = sqrtf(vs / (fmaxf(fc - 1.0f, 1.0f) + 1e-6f));
        if (cnt == 0) { mnv = 0.f; mxv = 0.f; }
        gl[r * 512 + 0 * 128 + d] = mean;
        gl[r * 512 + 1 * 128 + d] = mnv;
        gl[r * 512 + 2 * 128 + d] = mxv;
        gl[r * 512 + 3 * 128 + d] = sd;
    }
    __syncthreads();

    int col = t;
    float acc[8];
    float bv = bias[col];
#pragma unroll
    for (int r = 0; r < 8; ++r) acc[r] = bv;
#pragma unroll 4
    for (int k = 0; k < 512; ++k) {
        float wv = w[k * GD + col];
#pragma unroll
        for (int r = 0; r < 8; ++r) acc[r] += gl[r * 512 + k] * wv;
    }
#pragma unroll
    for (int r = 0; r < 8; ++r) {
        int rr = r0 + r;
        if (rr < B) out[(size_t)rr * GD + col] = acc[r];
    }
}

// ---------- launch ----------
extern "C" void kernel_launch(void* const* d_in, const int* in_sizes, int n_in,
                              void* d_out, int out_size, void* d_ws, size_t ws_size,
                              hipStream_t stream) {
    const int*   e_index = (const int*)d_in[0];
    const float* e       = (const float*)d_in[1];
    const int*   batch   = (const int*)d_in[2];
    const float* fc_w    = (const float*)d_in[3];
    const float* fc_b    = (const float*)d_in[4];
    float* out = (float*)d_out;

    int E = in_sizes[1] / DIMS;
    int B = out_size / GD;

    // workspace layout (all 4B-aligned)
    int* hist2 = (int*)d_ws;                         // NBLK*MAXB = 1 MB
    int* count = hist2 + (size_t)NBLK * MAXB;        // MAXB
    int* offs  = count + MAXB;                       // MAXB
    unsigned short* eb = (unsigned short*)(offs + MAXB);  // E ushorts
    int* perm  = (int*)(eb + (((size_t)E + 1) & ~(size_t)1)); // E
    float* pbuf = (float*)(perm + E);                // MAXB*PARTS*512 = 8 MB

    hist2_kernel<<<NBLK, 256, 0, stream>>>(e_index, batch, E, hist2, eb);
    scanall_kernel<<<1, MAXB, 0, stream>>>(hist2, count, offs);
    scatter_kernel<<<NBLK, 256, 0, stream>>>(eb, hist2, offs, E, perm);
    reduce_kernel<<<B * PARTS, 256, 0, stream>>>(e, perm, offs, count, pbuf);
    gemm_kernel<<<(B + 7) / 8, 256, 0, stream>>>(pbuf, count, fc_w, fc_b, out, B);
}

// Round 5
// 267.047 us; speedup vs baseline: 1.0698x; 1.0698x over previous
//
#include <hip/hip_runtime.h>
#include <math.h>

#define DIMS 128
#define GD 256
#define MAXB 1024
#define NSLOT 8   // edge slots per reduce block (256 thr / 32 dim-groups)
#define PARTS 4   // blocks per graph in reduce phase
#define NBLK 256  // block decomposition for histogram/scatter
#define SCH 8192  // max edges per scatter chunk (>= ceil(E/NBLK))

typedef float vfloat4 __attribute__((ext_vector_type(4)));

// ---------- helpers ----------
__device__ __forceinline__ float4 ldnt(const float* p) {
    vfloat4 v = __builtin_nontemporal_load(reinterpret_cast<const vfloat4*>(p));
    return make_float4(v.x, v.y, v.z, v.w);
}
__device__ __forceinline__ float4 f4_add(float4 a, float4 b) {
    return make_float4(a.x + b.x, a.y + b.y, a.z + b.z, a.w + b.w);
}
__device__ __forceinline__ float4 f4_min(float4 a, float4 b) {
    return make_float4(fminf(a.x, b.x), fminf(a.y, b.y), fminf(a.z, b.z), fminf(a.w, b.w));
}
__device__ __forceinline__ float4 f4_max(float4 a, float4 b) {
    return make_float4(fmaxf(a.x, b.x), fmaxf(a.y, b.y), fmaxf(a.z, b.z), fmaxf(a.w, b.w));
}

template <int OP>
__device__ __forceinline__ float4 comb(float4 a, float4 b) {
    if (OP == 0) return f4_add(a, b);
    if (OP == 1) return f4_min(a, b);
    return f4_max(a, b);
}

// reduce the 8 edge-slots (stride 32 in tid) down to slot 0; result valid for tid<32
template <int OP>
__device__ __forceinline__ float4 slot_reduce(float4 v, float4* red) {
    int t = threadIdx.x;
    __syncthreads();
    red[t] = v;
    __syncthreads();
    for (int off = 128; off >= 32; off >>= 1) {
        if (t < off) red[t] = comb<OP>(red[t], red[t + off]);
        __syncthreads();
    }
    return red[t & 31];
}

#define ACC(v) do { \
    sm = f4_add(sm, v); \
    sq = f4_add(sq, make_float4((v).x*(v).x, (v).y*(v).y, (v).z*(v).z, (v).w*(v).w)); \
    mn = f4_min(mn, v); mx = f4_max(mx, v); } while (0)

// ---------- K1: per-block histogram + graph-id cache ----------
__global__ void __launch_bounds__(256)
hist2_kernel(const int* __restrict__ e_index, const int* __restrict__ batch,
             int E, int* __restrict__ hist2, unsigned short* __restrict__ eb) {
    __shared__ int lh[MAXB];
    for (int i = threadIdx.x; i < MAXB; i += 256) lh[i] = 0;
    __syncthreads();
    int b = blockIdx.x;
    int CH = (E + NBLK - 1) / NBLK;
    int lo = b * CH;
    int hi = min(E, lo + CH);
    for (int j = lo + threadIdx.x; j < hi; j += 256) {
        int node = e_index[E + j];       // e_index[1][j]
        int g = batch[node];
        eb[j] = (unsigned short)g;
        atomicAdd(&lh[g], 1);            // LDS atomic only
    }
    __syncthreads();
    for (int i = threadIdx.x; i < MAXB; i += 256)
        hist2[(size_t)b * MAXB + i] = lh[i];   // coalesced 4 KB per block
}

// ---------- K2: parallel column scan; one block per graph ----------
__global__ void __launch_bounds__(256)
colscan_kernel(int* __restrict__ hist2, int* __restrict__ count) {
    int g = blockIdx.x;
    int t = threadIdx.x;                 // == block index b (NBLK == 256)
    int v = hist2[(size_t)t * MAXB + g];
    __shared__ int ws[256];
    ws[t] = v;
    __syncthreads();
    for (int d = 1; d < 256; d <<= 1) {  // inclusive Hillis-Steele
        int x = (t >= d) ? ws[t - d] : 0;
        __syncthreads();
        ws[t] += x;
        __syncthreads();
    }
    hist2[(size_t)t * MAXB + g] = ws[t] - v;   // exclusive prefix per (b,g)
    if (t == 255) count[g] = ws[255];
}

// ---------- K3: LDS-binned scatter; derives global offs from count in-block ----------
__global__ void __launch_bounds__(256)
scatter_kernel(const unsigned short* __restrict__ eb, const int* __restrict__ hist2,
               const int* __restrict__ count, int E,
               int* __restrict__ perm, int* __restrict__ offs) {
    __shared__ int lhist[MAXB];
    __shared__ int lofs[MAXB];
    __shared__ int lcur[MAXB];
    __shared__ int lbase[MAXB];
    __shared__ int ws[256];
    __shared__ int bin[SCH];
    int b = blockIdx.x;
    int t = threadIdx.x;
    int CH = (E + NBLK - 1) / NBLK;
    int lo = b * CH;
    int hi = min(E, lo + CH);
    int base = t * 4;

    // --- global exclusive scan of count[] (4 per thread + block scan) ---
    int g0 = count[base + 0], g1 = count[base + 1], g2 = count[base + 2], g3 = count[base + 3];
    int gsum = g0 + g1 + g2 + g3;
    ws[t] = gsum;
    __syncthreads();
    for (int d = 1; d < 256; d <<= 1) {
        int x = (t >= d) ? ws[t - d] : 0;
        __syncthreads();
        ws[t] += x;
        __syncthreads();
    }
    int gexcl = ws[t] - gsum;
    int ob0 = gexcl, ob1 = gexcl + g0, ob2 = gexcl + g0 + g1, ob3 = gexcl + g0 + g1 + g2;
    if (b == 0) {                        // publish offs for reduce_kernel
        offs[base + 0] = ob0; offs[base + 1] = ob1;
        offs[base + 2] = ob2; offs[base + 3] = ob3;
    }
    lbase[base + 0] = ob0 + hist2[(size_t)b * MAXB + base + 0];
    lbase[base + 1] = ob1 + hist2[(size_t)b * MAXB + base + 1];
    lbase[base + 2] = ob2 + hist2[(size_t)b * MAXB + base + 2];
    lbase[base + 3] = ob3 + hist2[(size_t)b * MAXB + base + 3];
    lhist[base + 0] = 0; lhist[base + 1] = 0; lhist[base + 2] = 0; lhist[base + 3] = 0;
    __syncthreads();

    // --- local count ---
    for (int j = lo + t; j < hi; j += 256) atomicAdd(&lhist[eb[j]], 1);
    __syncthreads();

    // --- local exclusive scan over 1024 bins ---
    int c0 = lhist[base + 0], c1 = lhist[base + 1], c2 = lhist[base + 2], c3 = lhist[base + 3];
    int s0 = c0 + c1 + c2 + c3;
    ws[t] = s0;
    __syncthreads();
    for (int d = 1; d < 256; d <<= 1) {
        int x = (t >= d) ? ws[t - d] : 0;
        __syncthreads();
        ws[t] += x;
        __syncthreads();
    }
    int excl = ws[t] - s0;
    lofs[base + 0] = excl;
    lofs[base + 1] = excl + c0;
    lofs[base + 2] = excl + c0 + c1;
    lofs[base + 3] = excl + c0 + c1 + c2;
    lcur[base + 0] = excl;
    lcur[base + 1] = excl + c0;
    lcur[base + 2] = excl + c0 + c1;
    lcur[base + 3] = excl + c0 + c1 + c2;
    __syncthreads();

    // --- bin edge ids into LDS ---
    for (int j = lo + t; j < hi; j += 256) {
        int g = eb[j];
        int r = atomicAdd(&lcur[g], 1);
        bin[r] = j;
    }
    __syncthreads();

    // --- flush: 8-lane groups write each graph's run contiguously ---
    int grp = t >> 3, sub = t & 7;   // 32 groups of 8
    for (int g = grp; g < MAXB; g += 32) {
        int sfrom = lofs[g];
        int n = lcur[g] - sfrom;
        int dst = lbase[g];
        for (int k = sub; k < n; k += 8)
            perm[dst + k] = bin[sfrom + k];
    }
}

// ---------- K4: one block per (graph, part): partials {sum,min,max,sumsq} ----------
__global__ void __launch_bounds__(256)
reduce_kernel(const float* __restrict__ e, const int* __restrict__ perm,
              const int* __restrict__ offs, const int* __restrict__ count,
              float* __restrict__ pbuf) {
    int bid = blockIdx.x;
    int g = bid >> 2;                // PARTS == 4
    int p = bid & 3;
    int start = offs[g];
    int cnt = count[g];
    int chunk = (cnt + PARTS - 1) / PARTS;
    int base = start + p * chunk;
    int cnt_p = cnt - p * chunk;
    if (cnt_p > chunk) cnt_p = chunk;
    if (cnt_p < 0) cnt_p = 0;
    const int* pp = perm + base;

    int c = threadIdx.x & 31;   // dim group: dims 4c..4c+3
    int s = threadIdx.x >> 5;   // edge slot 0..7

    float4 sm = make_float4(0.f, 0.f, 0.f, 0.f);
    float4 sq = make_float4(0.f, 0.f, 0.f, 0.f);
    float4 mn = make_float4(INFINITY, INFINITY, INFINITY, INFINITY);
    float4 mx = make_float4(-INFINITY, -INFINITY, -INFINITY, -INFINITY);

    int i = s;
    // 4-row software pipeline: indices prefetched one quad ahead, 4 loads in flight
    if (i + 3 * NSLOT < cnt_p) {
        int ia0 = pp[i], ia1 = pp[i + NSLOT], ia2 = pp[i + 2 * NSLOT], ia3 = pp[i + 3 * NSLOT];
        while (true) {
            int ni = i + 4 * NSLOT;
            int na0 = 0, na1 = 0, na2 = 0, na3 = 0;
            bool nok = (ni + 3 * NSLOT < cnt_p);
            if (nok) { na0 = pp[ni]; na1 = pp[ni + NSLOT]; na2 = pp[ni + 2 * NSLOT]; na3 = pp[ni + 3 * NSLOT]; }
            float4 v0 = ldnt(e + (size_t)ia0 * DIMS + c * 4);
            float4 v1 = ldnt(e + (size_t)ia1 * DIMS + c * 4);
            float4 v2 = ldnt(e + (size_t)ia2 * DIMS + c * 4);
            float4 v3 = ldnt(e + (size_t)ia3 * DIMS + c * 4);
            ACC(v0); ACC(v1); ACC(v2); ACC(v3);
            i = ni;
            if (!nok) break;
            ia0 = na0; ia1 = na1; ia2 = na2; ia3 = na3;
        }
    }
    for (; i < cnt_p; i += NSLOT) {
        int r = pp[i];
        float4 v = ldnt(e + (size_t)r * DIMS + c * 4);
        ACC(v);
    }

    __shared__ float4 red[256];
    float4 smr = slot_reduce<0>(sm, red);
    float4 mnr = slot_reduce<1>(mn, red);
    float4 mxr = slot_reduce<2>(mx, red);
    float4 sqr = slot_reduce<0>(sq, red);

    if (threadIdx.x < 32) {
        float* row = pbuf + (size_t)bid * (4 * DIMS);
        int d0 = c * 4;
        *reinterpret_cast<float4*>(row + 0 * DIMS + d0) = smr;
        *reinterpret_cast<float4*>(row + 1 * DIMS + d0) = mnr;
        *reinterpret_cast<float4*>(row + 2 * DIMS + d0) = mxr;
        *reinterpret_cast<float4*>(row + 3 * DIMS + d0) = sqr;
    }
}

// ---------- K5: fused combine + GEMM; 8 graph rows per block ----------
__global__ void __launch_bounds__(256)
gemm_kernel(const float* __restrict__ pbuf, const int* __restrict__ count,
            const float* __restrict__ w, const float* __restrict__ bias,
            float* __restrict__ out, int B) {
    __shared__ float gl[8 * 512];
    int r0 = blockIdx.x * 8;
    int t = threadIdx.x;
    // combine PARTS partials and finalize straight into LDS
#pragma unroll
    for (int q = 0; q < 4; ++q) {
        int pair = q * 256 + t;      // 0..1023 = (r,d)
        int r = pair >> 7;           // 0..7
        int d = pair & 127;
        int g = r0 + r;
        float sm = 0.f, sq = 0.f, mnv = INFINITY, mxv = -INFINITY;
        int cnt = 0;
        if (g < B) {
            cnt = count[g];
            const float* pb = pbuf + (size_t)g * PARTS * 512;
#pragma unroll
            for (int p = 0; p < PARTS; ++p) {
                const float* row = pb + p * 512;
                sm += row[d];
                mnv = fminf(mnv, row[128 + d]);
                mxv = fmaxf(mxv, row[256 + d]);
                sq += row[384 + d];
            }
        }
        float fc = (float)cnt;
        float fcm = fmaxf(fc, 1.0f);
        float mean = sm / fcm;
        float vs = fmaxf(sq - sm * mean, 0.f);
        float sd = sqrtf(vs / (fmaxf(fc - 1.0f, 1.0f) + 1e-6f));
        if (cnt == 0) { mnv = 0.f; mxv = 0.f; }
        gl[r * 512 + 0 * 128 + d] = mean;
        gl[r * 512 + 1 * 128 + d] = mnv;
        gl[r * 512 + 2 * 128 + d] = mxv;
        gl[r * 512 + 3 * 128 + d] = sd;
    }
    __syncthreads();

    int col = t;
    float acc[8];
    float bv = bias[col];
#pragma unroll
    for (int r = 0; r < 8; ++r) acc[r] = bv;
#pragma unroll 4
    for (int k = 0; k < 512; ++k) {
        float wv = w[k * GD + col];
#pragma unroll
        for (int r = 0; r < 8; ++r) acc[r] += gl[r * 512 + k] * wv;
    }
#pragma unroll
    for (int r = 0; r < 8; ++r) {
        int rr = r0 + r;
        if (rr < B) out[(size_t)rr * GD + col] = acc[r];
    }
}

// ---------- launch ----------
extern "C" void kernel_launch(void* const* d_in, const int* in_sizes, int n_in,
                              void* d_out, int out_size, void* d_ws, size_t ws_size,
                              hipStream_t stream) {
    const int*   e_index = (const int*)d_in[0];
    const float* e       = (const float*)d_in[1];
    const int*   batch   = (const int*)d_in[2];
    const float* fc_w    = (const float*)d_in[3];
    const float* fc_b    = (const float*)d_in[4];
    float* out = (float*)d_out;

    int E = in_sizes[1] / DIMS;
    int B = out_size / GD;

    // workspace layout (all 4B-aligned)
    int* hist2 = (int*)d_ws;                         // NBLK*MAXB = 1 MB
    int* count = hist2 + (size_t)NBLK * MAXB;        // MAXB
    int* offs  = count + MAXB;                       // MAXB
    unsigned short* eb = (unsigned short*)(offs + MAXB);  // E ushorts
    int* perm  = (int*)(eb + (((size_t)E + 1) & ~(size_t)1)); // E
    float* pbuf = (float*)(perm + E);                // MAXB*PARTS*512 = 8 MB

    hist2_kernel<<<NBLK, 256, 0, stream>>>(e_index, batch, E, hist2, eb);
    colscan_kernel<<<MAXB, 256, 0, stream>>>(hist2, count);
    scatter_kernel<<<NBLK, 256, 0, stream>>>(eb, hist2, count, E, perm, offs);
    reduce_kernel<<<B * PARTS, 256, 0, stream>>>(e, perm, offs, count, pbuf);
    gemm_kernel<<<(B + 7) / 8, 256, 0, stream>>>(pbuf, count, fc_w, fc_b, out, B);
}

// Round 6
// 262.296 us; speedup vs baseline: 1.0892x; 1.0181x over previous
//
#include <hip/hip_runtime.h>
#include <math.h>

#define DIMS 128
#define GD 256
#define MAXB 1024
#define NSLOT 8   // edge slots per reduce block (256 thr / 32 dim-groups)
#define NBLK 256  // block decomposition for histogram/scatter
#define SCH 8192  // max edges per scatter chunk (>= ceil(E/NBLK))

typedef float vfloat4 __attribute__((ext_vector_type(4)));

// ---------- helpers ----------
__device__ __forceinline__ float4 ldnt(const float* p) {
    vfloat4 v = __builtin_nontemporal_load(reinterpret_cast<const vfloat4*>(p));
    return make_float4(v.x, v.y, v.z, v.w);
}
__device__ __forceinline__ float4 f4_add(float4 a, float4 b) {
    return make_float4(a.x + b.x, a.y + b.y, a.z + b.z, a.w + b.w);
}
__device__ __forceinline__ float4 f4_min(float4 a, float4 b) {
    return make_float4(fminf(a.x, b.x), fminf(a.y, b.y), fminf(a.z, b.z), fminf(a.w, b.w));
}
__device__ __forceinline__ float4 f4_max(float4 a, float4 b) {
    return make_float4(fmaxf(a.x, b.x), fmaxf(a.y, b.y), fmaxf(a.z, b.z), fmaxf(a.w, b.w));
}

#define ACC(v) do { \
    sm = f4_add(sm, v); \
    sq = f4_add(sq, make_float4((v).x*(v).x, (v).y*(v).y, (v).z*(v).z, (v).w*(v).w)); \
    mn = f4_min(mn, v); mx = f4_max(mx, v); } while (0)

// ---------- K1: per-block histogram (raw counts) + graph-id cache ----------
__global__ void __launch_bounds__(256)
hist2_kernel(const int* __restrict__ e_index, const int* __restrict__ batch,
             int E, int* __restrict__ hist2r, unsigned short* __restrict__ eb) {
    __shared__ int lh[MAXB];
    for (int i = threadIdx.x; i < MAXB; i += 256) lh[i] = 0;
    __syncthreads();
    int b = blockIdx.x;
    int CH = (E + NBLK - 1) / NBLK;
    int lo = b * CH;
    int hi = min(E, lo + CH);
    for (int j = lo + threadIdx.x; j < hi; j += 256) {
        int node = e_index[E + j];       // e_index[1][j]
        int g = batch[node];
        eb[j] = (unsigned short)g;
        atomicAdd(&lh[g], 1);            // LDS atomic only
    }
    __syncthreads();
    for (int i = threadIdx.x; i < MAXB; i += 256)
        hist2r[(size_t)b * MAXB + i] = lh[i];   // coalesced 4 KB per block
}

// ---------- K2: parallel column scan; raw -> scanned (separate buffer) ----------
__global__ void __launch_bounds__(256)
colscan_kernel(const int* __restrict__ hist2r, int* __restrict__ hist2s,
               int* __restrict__ count) {
    int g = blockIdx.x;
    int t = threadIdx.x;                 // == block index b (NBLK == 256)
    int v = hist2r[(size_t)t * MAXB + g];
    __shared__ int ws[256];
    ws[t] = v;
    __syncthreads();
    for (int d = 1; d < 256; d <<= 1) {  // inclusive Hillis-Steele
        int x = (t >= d) ? ws[t - d] : 0;
        __syncthreads();
        ws[t] += x;
        __syncthreads();
    }
    hist2s[(size_t)t * MAXB + g] = ws[t] - v;   // exclusive prefix per (b,g)
    if (t == 255) count[g] = ws[255];
}

// ---------- K3: LDS-binned scatter; local counts loaded (no recount pass) ----------
__global__ void __launch_bounds__(256)
scatter_kernel(const unsigned short* __restrict__ eb, const int* __restrict__ hist2r,
               const int* __restrict__ hist2s, const int* __restrict__ count, int E,
               int* __restrict__ perm, int* __restrict__ offs) {
    __shared__ int lofs[MAXB];
    __shared__ int lcur[MAXB];
    __shared__ int lbase[MAXB];
    __shared__ int ws[256];
    __shared__ int bin[SCH];
    int b = blockIdx.x;
    int t = threadIdx.x;
    int CH = (E + NBLK - 1) / NBLK;
    int lo = b * CH;
    int hi = min(E, lo + CH);
    int base = t * 4;

    // --- global exclusive scan of count[] (4 per thread + block scan) ---
    int g0 = count[base + 0], g1 = count[base + 1], g2 = count[base + 2], g3 = count[base + 3];
    int gsum = g0 + g1 + g2 + g3;
    ws[t] = gsum;
    __syncthreads();
    for (int d = 1; d < 256; d <<= 1) {
        int x = (t >= d) ? ws[t - d] : 0;
        __syncthreads();
        ws[t] += x;
        __syncthreads();
    }
    int gexcl = ws[t] - gsum;
    int ob0 = gexcl, ob1 = gexcl + g0, ob2 = gexcl + g0 + g1, ob3 = gexcl + g0 + g1 + g2;
    if (b == 0) {                        // publish offs for reduce_kernel
        offs[base + 0] = ob0; offs[base + 1] = ob1;
        offs[base + 2] = ob2; offs[base + 3] = ob3;
    }
    lbase[base + 0] = ob0 + hist2s[(size_t)b * MAXB + base + 0];
    lbase[base + 1] = ob1 + hist2s[(size_t)b * MAXB + base + 1];
    lbase[base + 2] = ob2 + hist2s[(size_t)b * MAXB + base + 2];
    lbase[base + 3] = ob3 + hist2s[(size_t)b * MAXB + base + 3];
    __syncthreads();

    // --- local exclusive scan over 1024 bins (counts loaded, not recomputed) ---
    int c0 = hist2r[(size_t)b * MAXB + base + 0];
    int c1 = hist2r[(size_t)b * MAXB + base + 1];
    int c2 = hist2r[(size_t)b * MAXB + base + 2];
    int c3 = hist2r[(size_t)b * MAXB + base + 3];
    int s0 = c0 + c1 + c2 + c3;
    ws[t] = s0;
    __syncthreads();
    for (int d = 1; d < 256; d <<= 1) {
        int x = (t >= d) ? ws[t - d] : 0;
        __syncthreads();
        ws[t] += x;
        __syncthreads();
    }
    int excl = ws[t] - s0;
    lofs[base + 0] = excl;
    lofs[base + 1] = excl + c0;
    lofs[base + 2] = excl + c0 + c1;
    lofs[base + 3] = excl + c0 + c1 + c2;
    lcur[base + 0] = excl;
    lcur[base + 1] = excl + c0;
    lcur[base + 2] = excl + c0 + c1;
    lcur[base + 3] = excl + c0 + c1 + c2;
    __syncthreads();

    // --- bin edge ids into LDS ---
    for (int j = lo + t; j < hi; j += 256) {
        int g = eb[j];
        int r = atomicAdd(&lcur[g], 1);
        bin[r] = j;
    }
    __syncthreads();

    // --- flush: 8-lane groups write each graph's run contiguously ---
    int grp = t >> 3, sub = t & 7;   // 32 groups of 8
    for (int g = grp; g < MAXB; g += 32) {
        int sfrom = lofs[g];
        int n = lcur[g] - sfrom;
        int dst = lbase[g];
        for (int k = sub; k < n; k += 8)
            perm[dst + k] = bin[sfrom + k];
    }
}

// ---------- K4: one block per graph: full stats -> gbuf[g][512] ----------
__global__ void __launch_bounds__(256)
reduce_kernel(const float* __restrict__ e, const int* __restrict__ perm,
              const int* __restrict__ offs, const int* __restrict__ count,
              float* __restrict__ gbuf) {
    int g = blockIdx.x;
    int start = offs[g];
    int cnt = count[g];
    const int* pp = perm + start;

    int c = threadIdx.x & 31;   // dim group: dims 4c..4c+3
    int s = threadIdx.x >> 5;   // edge slot 0..7

    float4 sm = make_float4(0.f, 0.f, 0.f, 0.f);
    float4 sq = make_float4(0.f, 0.f, 0.f, 0.f);
    float4 mn = make_float4(INFINITY, INFINITY, INFINITY, INFINITY);
    float4 mx = make_float4(-INFINITY, -INFINITY, -INFINITY, -INFINITY);

    int i = s;
    // 4-row software pipeline: indices prefetched one quad ahead, 4 loads in flight
    if (i + 3 * NSLOT < cnt) {
        int ia0 = pp[i], ia1 = pp[i + NSLOT], ia2 = pp[i + 2 * NSLOT], ia3 = pp[i + 3 * NSLOT];
        while (true) {
            int ni = i + 4 * NSLOT;
            int na0 = 0, na1 = 0, na2 = 0, na3 = 0;
            bool nok = (ni + 3 * NSLOT < cnt);
            if (nok) { na0 = pp[ni]; na1 = pp[ni + NSLOT]; na2 = pp[ni + 2 * NSLOT]; na3 = pp[ni + 3 * NSLOT]; }
            float4 v0 = ldnt(e + (size_t)ia0 * DIMS + c * 4);
            float4 v1 = ldnt(e + (size_t)ia1 * DIMS + c * 4);
            float4 v2 = ldnt(e + (size_t)ia2 * DIMS + c * 4);
            float4 v3 = ldnt(e + (size_t)ia3 * DIMS + c * 4);
            ACC(v0); ACC(v1); ACC(v2); ACC(v3);
            i = ni;
            if (!nok) break;
            ia0 = na0; ia1 = na1; ia2 = na2; ia3 = na3;
        }
    }
    for (; i < cnt; i += NSLOT) {
        int r = pp[i];
        float4 v = ldnt(e + (size_t)r * DIMS + c * 4);
        ACC(v);
    }

    // single-sync epilogue: stage all 4 stats, combine 8 slots serially
    __shared__ float4 red[4][NSLOT][32];   // 16 KB
    red[0][s][c] = sm;
    red[1][s][c] = mn;
    red[2][s][c] = mx;
    red[3][s][c] = sq;
    __syncthreads();

    int t = threadIdx.x;
    if (t < 128) {
        int stat = t >> 5;      // 0=sum 1=min 2=max 3=sumsq(->std)
        int cc = t & 31;
        float4 a = red[stat][0][cc];
        if (stat == 1) {
#pragma unroll
            for (int k = 1; k < NSLOT; ++k) a = f4_min(a, red[1][k][cc]);
        } else if (stat == 2) {
#pragma unroll
            for (int k = 1; k < NSLOT; ++k) a = f4_max(a, red[2][k][cc]);
        } else {
#pragma unroll
            for (int k = 1; k < NSLOT; ++k) a = f4_add(a, red[stat][k][cc]);
        }
        float fc = (float)cnt;
        float fcm = fmaxf(fc, 1.0f);
        float4 r;
        if (stat == 0) {
            r = make_float4(a.x / fcm, a.y / fcm, a.z / fcm, a.w / fcm);
        } else if (stat == 1 || stat == 2) {
            r = (cnt == 0) ? make_float4(0.f, 0.f, 0.f, 0.f) : a;
        } else {
            float4 smr = red[0][0][cc];
#pragma unroll
            for (int k = 1; k < NSLOT; ++k) smr = f4_add(smr, red[0][k][cc]);
            float4 mean = make_float4(smr.x / fcm, smr.y / fcm, smr.z / fcm, smr.w / fcm);
            float denom = fmaxf(fc - 1.0f, 1.0f) + 1e-6f;
            r = make_float4(sqrtf(fmaxf(a.x - smr.x * mean.x, 0.f) / denom),
                            sqrtf(fmaxf(a.y - smr.y * mean.y, 0.f) / denom),
                            sqrtf(fmaxf(a.z - smr.z * mean.z, 0.f) / denom),
                            sqrtf(fmaxf(a.w - smr.w * mean.w, 0.f) / denom));
        }
        *reinterpret_cast<float4*>(gbuf + (size_t)g * 512 + stat * DIMS + cc * 4) = r;
    }
}

// ---------- K5: GEMM; 8 graph rows per block ----------
__global__ void __launch_bounds__(256)
gemm_kernel(const float* __restrict__ gbuf, const float* __restrict__ w,
            const float* __restrict__ bias, float* __restrict__ out, int B) {
    __shared__ float gl[8 * 512];
    int r0 = blockIdx.x * 8;
    int t = threadIdx.x;
    for (int i = t; i < 8 * 512; i += 256) {
        int r = r0 + (i >> 9);
        gl[i] = (r < B) ? gbuf[(size_t)r0 * 512 + i] : 0.f;
    }
    __syncthreads();

    int col = t;
    float acc[8];
    float bv = bias[col];
#pragma unroll
    for (int r = 0; r < 8; ++r) acc[r] = bv;
#pragma unroll 4
    for (int k = 0; k < 512; ++k) {
        float wv = w[k * GD + col];
#pragma unroll
        for (int r = 0; r < 8; ++r) acc[r] += gl[r * 512 + k] * wv;
    }
#pragma unroll
    for (int r = 0; r < 8; ++r) {
        int rr = r0 + r;
        if (rr < B) out[(size_t)rr * GD + col] = acc[r];
    }
}

// ---------- launch ----------
extern "C" void kernel_launch(void* const* d_in, const int* in_sizes, int n_in,
                              void* d_out, int out_size, void* d_ws, size_t ws_size,
                              hipStream_t stream) {
    const int*   e_index = (const int*)d_in[0];
    const float* e       = (const float*)d_in[1];
    const int*   batch   = (const int*)d_in[2];
    const float* fc_w    = (const float*)d_in[3];
    const float* fc_b    = (const float*)d_in[4];
    float* out = (float*)d_out;

    int E = in_sizes[1] / DIMS;
    int B = out_size / GD;

    // workspace layout (all 4B-aligned)
    int* hist2r = (int*)d_ws;                          // NBLK*MAXB = 1 MB (raw counts)
    int* hist2s = hist2r + (size_t)NBLK * MAXB;        // NBLK*MAXB = 1 MB (scanned)
    int* count  = hist2s + (size_t)NBLK * MAXB;        // MAXB
    int* offs   = count + MAXB;                        // MAXB
    unsigned short* eb = (unsigned short*)(offs + MAXB);      // E ushorts
    int* perm   = (int*)(eb + (((size_t)E + 1) & ~(size_t)1)); // E
    float* gbuf = (float*)(perm + E);                  // MAXB*512 floats

    hist2_kernel<<<NBLK, 256, 0, stream>>>(e_index, batch, E, hist2r, eb);
    colscan_kernel<<<MAXB, 256, 0, stream>>>(hist2r, hist2s, count);
    scatter_kernel<<<NBLK, 256, 0, stream>>>(eb, hist2r, hist2s, count, E, perm, offs);
    reduce_kernel<<<MAXB, 256, 0, stream>>>(e, perm, offs, count, gbuf);
    gemm_kernel<<<(B + 7) / 8, 256, 0, stream>>>(gbuf, fc_w, fc_b, out, B);
}